// Round 6
// baseline (57.449 us; speedup 1.0000x reference)
//
#include <hip/hip_runtime.h>
#include <hip/hip_bf16.h>

#define NQ 16384
#define NKV 4096
#define EPSF 1e-5f
// 1/sqrt(8) * log2(e): folds the exp2 conversion into K-hat
#define SCALE2 0.5100604576761344f
// 0.1 / log2(e) = 0.1*ln2: compensates relu weights scaled by log2e
#define C1 0.06931471805599453f

typedef float f32x4 __attribute__((ext_vector_type(4)));
typedef short s16x4 __attribute__((ext_vector_type(4)));

union U2S4 { uint2 u; s16x4 s; };

#if __has_builtin(__builtin_amdgcn_mfma_f32_16x16x16bf16_1k)
#define MFMA16(a, b, c) __builtin_amdgcn_mfma_f32_16x16x16bf16_1k((a), (b), (c), 0, 0, 0)
#else
static __device__ __forceinline__ f32x4 mfma16_asm(s16x4 a, s16x4 b, f32x4 c) {
    asm volatile("v_mfma_f32_16x16x16_bf16 %0, %1, %2, %0" : "+v"(c) : "v"(a), "v"(b));
    return c;
}
#define MFMA16(a, b, c) mfma16_asm((a), (b), (c))
#endif

#if __has_builtin(__builtin_amdgcn_exp2f)
#define EXP2F(x) __builtin_amdgcn_exp2f(x)
#else
#define EXP2F(x) exp2f(x)
#endif

// native packed f32->bf16 (RNE)
__device__ __forceinline__ unsigned int pk_bf16(float a, float b) {
    unsigned int r;
    asm("v_cvt_pk_bf16_f32 %0, %1, %2" : "=v"(r) : "v"(a), "v"(b));
    return r;
}

// ---------------- Kernel A: K/V preproc (LN + K/V proj -> bf16 tiles) ----------------
// KH:  [4096][16] bf16 (scaled by log2e/sqrt8, cols 8..15 zero) -> 512B per 16-key tile
// VTT: [256][16][16] bf16 tile-major (tile t, row d, col kc); row 8 = ones, 9..15 = 0
__global__ __launch_bounds__(64) void kv_kernel(
        const float* __restrict__ y, const float* __restrict__ Wk,
        const float* __restrict__ Wv, const float* __restrict__ ln_w,
        const float* __restrict__ ln_b,
        ushort* __restrict__ KH, ushort* __restrict__ VTT) {
    int r = blockIdx.x * 64 + threadIdx.x;
    if (r >= NKV) return;
    const float* src = y + (size_t)r * 8;
    float4 a = ((const float4*)src)[0];
    float4 b = ((const float4*)src)[1];
    float t[8] = {a.x,a.y,a.z,a.w,b.x,b.y,b.z,b.w};
    float mu = 0.f;
    #pragma unroll
    for (int i = 0; i < 8; i++) mu += t[i];
    mu *= 0.125f;
    float var = 0.f;
    #pragma unroll
    for (int i = 0; i < 8; i++) { float d = t[i] - mu; var += d * d; }
    var *= 0.125f;
    float rs = rsqrtf(var + EPSF);
    float z[8];
    #pragma unroll
    for (int i = 0; i < 8; i++) z[i] = (t[i] - mu) * rs * ln_w[i] + ln_b[i];

    float ok[8], ov[8];
    #pragma unroll
    for (int oo = 0; oo < 8; oo++) {
        float ak = 0.f, av = 0.f;
        #pragma unroll
        for (int i = 0; i < 8; i++) { ak += Wk[oo*8+i]*z[i]; av += Wv[oo*8+i]*z[i]; }
        ok[oo] = ak * SCALE2; ov[oo] = av;
    }
    uint4 lo, hi;
    lo.x = pk_bf16(ok[0],ok[1]); lo.y = pk_bf16(ok[2],ok[3]);
    lo.z = pk_bf16(ok[4],ok[5]); lo.w = pk_bf16(ok[6],ok[7]);
    hi.x = hi.y = hi.z = hi.w = 0u;
    uint4* dst = (uint4*)(KH + (size_t)r * 16);
    dst[0] = lo; dst[1] = hi;

    ushort* vt = VTT + (size_t)(r >> 4) * 256 + (r & 15);
    #pragma unroll
    for (int d = 0; d < 8; d++) {
        unsigned int p = pk_bf16(ov[d], 0.f);
        vt[d * 16] = (ushort)(p & 0xFFFF);
    }
    vt[8 * 16] = 0x3F80;   // 1.0 -> Z/R accumulator row
    #pragma unroll
    for (int d = 9; d < 16; d++) vt[d * 16] = 0;
}

// ---------------- Kernel B: fully fused block ----------------
// 256 blocks x 512 thr; block owns 64 queries. Phases:
//  P0: threads 0..63 LN+Q-proj their query row -> Qlds (bf16, zero-padded);
//      threads 64..191 stage W3 into LDS.
//  P1: main loop. 8 waves split keys 8-way (512 keys = 32 tiles each); per iter
//      ONE K-tile + ONE V-tile load feed 4 QK-MFMAs + 8 PV-MFMAs (4 q-frags).
//      V row 8 = ones -> Z/R ride in the PV accumulators. Depth-2 pipelined loads.
//  P2: LDS combine (128 threads) -> smooth-softmax epilogue + residual-1 -> Z1lds.
//  P3: MLP 8->64->64->8 (8 threads/row) + residual-2 -> out. No Z1 HBM round trip.
__global__ __launch_bounds__(512) void fused_kernel(
        const float* __restrict__ x,  const float* __restrict__ Wq,
        const float* __restrict__ ln_w, const float* __restrict__ ln_b,
        const ushort* __restrict__ KH, const ushort* __restrict__ VTT,
        const float* __restrict__ W1, const float* __restrict__ b1,
        const float* __restrict__ W2, const float* __restrict__ b2,
        const float* __restrict__ W3, const float* __restrict__ b3,
        float* __restrict__ out) {
    __shared__ ushort Qlds[64][16];
    __shared__ f32x4 Le[8][4][48];
    __shared__ f32x4 Lr[8][4][48];
    __shared__ float Z1lds[64][8];
    __shared__ float W3s[512];

    const int tid  = threadIdx.x;
    const int w    = tid >> 6;        // 0..7
    const int lane = tid & 63;
    const int grp  = lane >> 4;
    const int qi   = lane & 15;
    const int q0   = blockIdx.x * 64;

    // ---- P0: Q projection into LDS; W3 staging ----
    if (tid < 64) {
        const float* src = x + (size_t)(q0 + tid) * 8;
        float4 a = ((const float4*)src)[0];
        float4 b = ((const float4*)src)[1];
        float t[8] = {a.x,a.y,a.z,a.w,b.x,b.y,b.z,b.w};
        float mu = 0.f;
        #pragma unroll
        for (int i = 0; i < 8; i++) mu += t[i];
        mu *= 0.125f;
        float var = 0.f;
        #pragma unroll
        for (int i = 0; i < 8; i++) { float d = t[i] - mu; var += d * d; }
        var *= 0.125f;
        float rs = rsqrtf(var + EPSF);
        float z[8];
        #pragma unroll
        for (int i = 0; i < 8; i++) z[i] = (t[i] - mu) * rs * ln_w[i] + ln_b[i];
        float o[8];
        #pragma unroll
        for (int oo = 0; oo < 8; oo++) {
            float acc = 0.f;
            #pragma unroll
            for (int i = 0; i < 8; i++) acc += Wq[oo*8+i] * z[i];
            o[oo] = acc;
        }
        uint4 lo, hi;
        lo.x = pk_bf16(o[0],o[1]); lo.y = pk_bf16(o[2],o[3]);
        lo.z = pk_bf16(o[4],o[5]); lo.w = pk_bf16(o[6],o[7]);
        hi.x = hi.y = hi.z = hi.w = 0u;
        uint4* qdst = (uint4*)&Qlds[tid][0];
        qdst[0] = lo; qdst[1] = hi;
    } else if (tid < 192) {
        int i = (tid - 64) * 4;
        *(float4*)&W3s[i] = *(const float4*)&W3[i];
    }
    __syncthreads();

    // ---- P1: main attention loop ----
    U2S4 qf[4];
    #pragma unroll
    for (int f = 0; f < 4; f++)
        qf[f].u = *(const uint2*)&Qlds[16*f + qi][4*grp];

    const ushort* kp = KH  + (size_t)(w * 32) * 256 + qi * 16 + 4 * grp;
    const ushort* vp = VTT + (size_t)(w * 32) * 256 + qi * 16 + 4 * grp;

    f32x4 ae[4], ar[4];
    #pragma unroll
    for (int f = 0; f < 4; f++) { ae[f] = (f32x4){0,0,0,0}; ar[f] = (f32x4){0,0,0,0}; }

    U2S4 k0, v0, k1, v1, k2, v2;
    k0.u = *(const uint2*)kp;        v0.u = *(const uint2*)vp;
    k1.u = *(const uint2*)(kp+256);  v1.u = *(const uint2*)(vp+256);
    kp += 512; vp += 512;

    #pragma unroll 2
    for (int t = 0; t < 32; t++) {
        k2.u = *(const uint2*)kp;  v2.u = *(const uint2*)vp;   // over-reads 2 tiles
        kp += 256; vp += 256;                                   // past range: benign ws

        f32x4 s[4];
        #pragma unroll
        for (int f = 0; f < 4; f++)
            s[f] = MFMA16(k0.s, qf[f].s, ((f32x4){0.f,0.f,0.f,0.f}));

        #pragma unroll
        for (int f = 0; f < 4; f++) {
            float e0 = EXP2F(s[f][0]), e1 = EXP2F(s[f][1]);
            float e2 = EXP2F(s[f][2]), e3 = EXP2F(s[f][3]);
            float r0 = fmaxf(s[f][0],0.f), r1 = fmaxf(s[f][1],0.f);
            float r2 = fmaxf(s[f][2],0.f), r3 = fmaxf(s[f][3],0.f);
            U2S4 pe, pr;
            pe.u.x = pk_bf16(e0,e1); pe.u.y = pk_bf16(e2,e3);
            pr.u.x = pk_bf16(r0,r1); pr.u.y = pk_bf16(r2,r3);
            ae[f] = MFMA16(v0.s, pe.s, ae[f]);
            ar[f] = MFMA16(v0.s, pr.s, ar[f]);
        }

        k0 = k1; v0 = v1;
        k1 = k2; v1 = v2;
    }

    if (grp < 3) {                    // rows 0..11 (incl. ones-row 8) are consumed
        #pragma unroll
        for (int f = 0; f < 4; f++) { Le[w][f][lane] = ae[f]; Lr[w][f][lane] = ar[f]; }
    }
    __syncthreads();

    // ---- P2: combine + smooth-softmax + residual 1 -> Z1lds ----
    if (tid < 128) {
        const int g = tid >> 6, qloc = tid & 63;
        const int j = qloc >> 4, q = qloc & 15;
        f32x4 Ae = {0,0,0,0}, Ar = {0,0,0,0};
        float Z = 0.f, R = 0.f;
        #pragma unroll
        for (int w2 = 0; w2 < 8; w2++) {
            Ae += Le[w2][j][g*16+q];
            Ar += Lr[w2][j][g*16+q];
            Z  += Le[w2][j][32+q][0];   // C row 8 (ones) = sum of exp weights
            R  += Lr[w2][j][32+q][0];   // = sum of relu weights (x log2e)
        }
        float iz  = 1.0f / Z;
        float den = 1.0f / (C1 * R + 1.0f);
        float4 xr = *(const float4*)(x + (size_t)(q0 + qloc) * 8 + 4 * g);
        Z1lds[qloc][4*g+0] = (C1 * Ar[0] + Ae[0] * iz) * den + xr.x;
        Z1lds[qloc][4*g+1] = (C1 * Ar[1] + Ae[1] * iz) * den + xr.y;
        Z1lds[qloc][4*g+2] = (C1 * Ar[2] + Ae[2] * iz) * den + xr.z;
        Z1lds[qloc][4*g+3] = (C1 * Ar[3] + Ae[3] * iz) * den + xr.w;
    }
    __syncthreads();

    // ---- P3: LN + MLP (8->64->64->8) + residual 2 ----
    const int row = tid >> 3;         // 0..63
    const int og  = tid & 7;          // 8 hidden-2 units each (interleaved)

    float z1r[8];
    #pragma unroll
    for (int i = 0; i < 8; i++) z1r[i] = Z1lds[row][i];
    float mu = 0.f;
    #pragma unroll
    for (int i = 0; i < 8; i++) mu += z1r[i];
    mu *= 0.125f;
    float var = 0.f;
    #pragma unroll
    for (int i = 0; i < 8; i++) { float d = z1r[i] - mu; var += d * d; }
    var *= 0.125f;
    float rs2 = rsqrtf(var + EPSF);
    float z2[8];
    #pragma unroll
    for (int i = 0; i < 8; i++) z2[i] = (z1r[i] - mu) * rs2 * ln_w[i] + ln_b[i];

    float h[64];
    #pragma unroll
    for (int o = 0; o < 64; o++) {      // W1/b1 wave-uniform -> scalar loads
        float acc = b1[o];
        #pragma unroll
        for (int i = 0; i < 8; i++) acc += W1[o*8+i] * z2[i];
        h[o] = fmaxf(acc, 0.f);
    }

    float oacc[8];
    #pragma unroll
    for (int d = 0; d < 8; d++) oacc[d] = 0.f;
    #pragma unroll
    for (int oo = 0; oo < 8; oo++) {
        int o = og + 8 * oo;
        float a0 = 0.f, a1 = 0.f, a2 = 0.f, a3 = 0.f;
        const float4* w2r = (const float4*)(W2 + o * 64);
        #pragma unroll
        for (int i4 = 0; i4 < 16; i4++) {
            float4 wv = w2r[i4];
            a0 += wv.x * h[4*i4];   a1 += wv.y * h[4*i4+1];
            a2 += wv.z * h[4*i4+2]; a3 += wv.w * h[4*i4+3];
        }
        float act = fmaxf(b2[o] + ((a0 + a1) + (a2 + a3)), 0.f);
        #pragma unroll
        for (int d = 0; d < 8; d++) oacc[d] += W3s[d*64+o] * act;
    }

    #pragma unroll
    for (int m = 1; m <= 4; m <<= 1) {
        #pragma unroll
        for (int d = 0; d < 8; d++) oacc[d] += __shfl_xor(oacc[d], m);
    }
    if (og == 0) {
        float4* op = (float4*)(out + (size_t)(q0 + row) * 8);
        op[0] = make_float4(oacc[0]+b3[0]+z1r[0], oacc[1]+b3[1]+z1r[1],
                            oacc[2]+b3[2]+z1r[2], oacc[3]+b3[3]+z1r[3]);
        op[1] = make_float4(oacc[4]+b3[4]+z1r[4], oacc[5]+b3[5]+z1r[5],
                            oacc[6]+b3[6]+z1r[6], oacc[7]+b3[7]+z1r[7]);
    }
}

extern "C" void kernel_launch(void* const* d_in, const int* in_sizes, int n_in,
                              void* d_out, int out_size, void* d_ws, size_t ws_size,
                              hipStream_t stream) {
    const float* x   = (const float*)d_in[0];
    const float* y   = (const float*)d_in[1];
    const float* Wq  = (const float*)d_in[2];
    const float* Wk  = (const float*)d_in[3];
    const float* Wv  = (const float*)d_in[4];
    const float* W1  = (const float*)d_in[5];
    const float* b1  = (const float*)d_in[6];
    const float* W2  = (const float*)d_in[7];
    const float* b2  = (const float*)d_in[8];
    const float* W3  = (const float*)d_in[9];
    const float* b3  = (const float*)d_in[10];
    const float* lnw = (const float*)d_in[11];
    const float* lnb = (const float*)d_in[12];

    char* ws = (char*)d_ws;
    ushort* KH  = (ushort*)ws;                 // 131072 B
    ushort* VTT = (ushort*)(ws + 131072);      // 131072 B (+ prefetch over-read slack)
    float* out = (float*)d_out;

    kv_kernel<<<NKV / 64, 64, 0, stream>>>(y, Wk, Wv, lnw, lnb, KH, VTT);
    fused_kernel<<<NQ / 64, 512, 0, stream>>>(x, Wq, lnw, lnb, KH, VTT,
                                              W1, b1, W2, b2, W3, b3, out);
}